// Round 2
// baseline (575.629 us; speedup 1.0000x reference)
//
#include <hip/hip_runtime.h>
#include <math.h>

// N=4, C=256, H=W=32, NH=2, HD=128, MAX_DIS=7, WS=15, WW=225, T=sqrt(128)
// out: [hw=1024][n=4][c=256] fp32

__device__ __forceinline__ int iclamp(int v, int lo, int hi) {
    return v < lo ? lo : (v > hi ? hi : v);
}

// ---------------------------------------------------------------------------
// Shared GEMM body: Y(64x64 tile) = W[M,K] x X[K,1024] over k-tiles [kt0,kt1)
// flags: 1=RMW accumulate, 2=interleaved store (out[(col)*ldI + storeOff + row]),
//        4=atomicAdd output. bias added only when addBias.
// ---------------------------------------------------------------------------
__device__ __forceinline__
void gemm_body(const float* __restrict__ Wb, const float* __restrict__ Xb,
               const float* __restrict__ biasb, float* __restrict__ Yb,
               int M, int K, int kt0, int kt1, bool addBias, int flags,
               long storeOff, int ldI)
{
    __shared__ __align__(16) float sm[64 * 68];
    float* Ws = sm;              // [16][68] k-major, d contiguous
    float* Xs = sm + 16 * 68;    // [16][64] k-major, m contiguous

    const int row0 = blockIdx.y * 64;
    const int col0 = blockIdx.x * 64;
    const int tid = threadIdx.x;
    const int tx = tid & 15, ty = tid >> 4;

    float acc[4][4];
#pragma unroll
    for (int i = 0; i < 4; ++i)
#pragma unroll
        for (int j = 0; j < 4; ++j) acc[i][j] = 0.f;

    for (int kt = kt0; kt < kt1; ++kt) {
        const int c0 = kt * 16;
#pragma unroll
        for (int i = 0; i < 4; ++i) {
            int e = tid + i * 256;
            int cc = e & 15, dd = e >> 4;
            int gd = row0 + dd, gc = c0 + cc;
            float v = 0.f;
            if (gd < M && gc < K) v = Wb[(long)gd * K + gc];
            Ws[cc * 68 + dd] = v;
        }
#pragma unroll
        for (int i = 0; i < 4; ++i) {
            int e = tid + i * 256;
            int mm = e & 63, cc = e >> 6;
            int gc = c0 + cc;
            float v = 0.f;
            if (gc < K) v = Xb[((long)gc << 10) + col0 + mm];
            Xs[cc * 64 + mm] = v;
        }
        __syncthreads();
#pragma unroll
        for (int k = 0; k < 16; ++k) {
            const float4 a4 = *(const float4*)&Ws[k * 68 + ty * 4];
            const float4 b4 = *(const float4*)&Xs[k * 64 + tx * 4];
            float av[4] = {a4.x, a4.y, a4.z, a4.w};
            float bv[4] = {b4.x, b4.y, b4.z, b4.w};
#pragma unroll
            for (int i = 0; i < 4; ++i)
#pragma unroll
                for (int j = 0; j < 4; ++j) acc[i][j] += av[i] * bv[j];
        }
        __syncthreads();
    }

    if (!(flags & 2)) {
#pragma unroll
        for (int i = 0; i < 4; ++i) {
            int gd = row0 + ty * 4 + i;
            if (gd >= M) continue;
            float bvv = (addBias && biasb) ? biasb[gd] : 0.f;
            long yoff = ((long)gd << 10) + col0 + tx * 4;
            if (flags & 4) {
#pragma unroll
                for (int j = 0; j < 4; ++j)
                    atomicAdd(&Yb[yoff + j], acc[i][j] + bvv);
            } else {
                float4 r;
                r.x = acc[i][0] + bvv; r.y = acc[i][1] + bvv;
                r.z = acc[i][2] + bvv; r.w = acc[i][3] + bvv;
                if (flags & 1) {
                    float4 old = *(const float4*)&Yb[yoff];
                    r.x += old.x; r.y += old.y; r.z += old.z; r.w += old.w;
                }
                *(float4*)&Yb[yoff] = r;
            }
        }
    } else {
        // interleaved store via LDS transpose (k-loop ended with barrier)
        float* tile = sm;  // [64 m][68 d]
#pragma unroll
        for (int i = 0; i < 4; ++i) {
            float bvv = (addBias && biasb) ? biasb[row0 + ty * 4 + i] : 0.f;
#pragma unroll
            for (int j = 0; j < 4; ++j)
                tile[(tx * 4 + j) * 68 + ty * 4 + i] = acc[i][j] + bvv;
        }
        __syncthreads();
#pragma unroll
        for (int it = 0; it < 16; ++it) {
            int e = tid + it * 256;
            int dd = e & 63, mm = e >> 6;
            long off = (long)(col0 + mm) * ldI + storeOff + row0 + dd;
            if (flags & 4) atomicAdd(&Yb[off], tile[mm * 68 + dd]);
            else Yb[off] = tile[mm * 68 + dd];
        }
    }
}

__global__ __launch_bounds__(256)
void gemm_kernel(const float* __restrict__ W, const float* __restrict__ X,
                 const float* __restrict__ bias, float* __restrict__ Y,
                 int M, int K, long wStride, int wMod,
                 long xStride, long yStride, int biasStride, int biasMod,
                 int flags, int kSplit, int ldI)
{
    int b = blockIdx.z / kSplit;
    int ks = blockIdx.z - b * kSplit;
    int ktiles = (K + 15) >> 4;
    int kt0 = ks * ktiles / kSplit, kt1 = (ks + 1) * ktiles / kSplit;
    const float* Wb = W + (long)(b % wMod) * wStride;
    const float* Xb = X + (long)b * xStride;
    const float* biasb = bias ? (bias + (long)(b % biasMod) * biasStride) : nullptr;
    float* Yb; long storeOff = 0;
    if (flags & 2) { Yb = Y; storeOff = (long)b * M; }
    else           { Yb = Y + (long)b * yStride; }
    gemm_body(Wb, Xb, biasb, Yb, M, K, kt0, kt1, ks == 0, flags, storeOff, ldI);
}

// Q,K,V projections fused into one dispatch: b = z/kSplit in 0..11
__global__ __launch_bounds__(256)
void qkv_kernel(const float* __restrict__ q, const float* __restrict__ k,
                const float* __restrict__ v,
                const float* __restrict__ Wq, const float* __restrict__ Wk,
                const float* __restrict__ Wv,
                const float* __restrict__ bq, const float* __restrict__ bk,
                const float* __restrict__ bv,
                float* __restrict__ qp, float* __restrict__ kp,
                float* __restrict__ vp, int kSplit)
{
    int z = blockIdx.z;
    int b = z / kSplit, ks = z - b * kSplit;
    int sel = b >> 2, batch = b & 3;
    const float *W, *X, *bias; float* Y;
    if (sel == 0)      { W = Wq; X = q; bias = bq; Y = qp; }
    else if (sel == 1) { W = Wk; X = k; bias = bk; Y = kp; }
    else               { W = Wv; X = v; bias = bv; Y = vp; }
    int kt0 = ks * 16 / kSplit, kt1 = (ks + 1) * 16 / kSplit;
    gemm_body(W, X + ((long)batch << 18), bias, Y + ((long)batch << 18),
              256, 256, kt0, kt1, ks == 0, 4, 0, 0);
}

// ---------------------------------------------------------------------------
// scores + softmax: block = (ng, 1x8 pixel-row tile). 1024 blocks, ~12KB LDS.
// Reads rel logits from relattn, writes normalized attention back in place.
// ---------------------------------------------------------------------------
__global__ __launch_bounds__(256)
void scores_kernel(const float* __restrict__ qp, const float* __restrict__ kp,
                   float* __restrict__ relattn)
{
    __shared__ __align__(16) float qs[128 * 8];   // [c][8 px], scaled by 1/T
    __shared__ float qk[8 * 242];                 // [px][15*16 + 2]
    __shared__ float invl[8];

    const int tid = threadIdx.x;
    const int row = blockIdx.x >> 2;          // 0..31
    const int x0 = (blockIdx.x & 3) * 8;
    const int bz = blockIdx.y;                // n*2+g
    const long hoff = (long)((bz >> 1) * 256 + (bz & 1) * 128) << 10;
    const float* qh = qp + hoff;
    const float* kh = kp + hoff;
    float* relh = relattn + (long)bz * 230400;
    const int mm = row * 32 + x0;
    const float invT = 0.08838834764831845f;

    for (int e = tid; e < 1024; e += 256) {
        int c = e >> 3, px = e & 7;
        qs[c * 8 + px] = qh[((long)c << 10) + mm + px] * invT;
    }
    __syncthreads();

    // 240 tasks: (dy 15) x (pxg 2: 4px) x (dxg 8: 2dx)
    if (tid < 240) {
        int dy = tid >> 4;
        int r = tid & 15;
        int pxg = r & 1, dxg = r >> 1;
        int hy = row + dy - 7;
        int hyc = iclamp(hy, 0, 31);
        bool vy = (hy >= 0) && (hy < 32);
        int hx0 = x0 + pxg * 4 + dxg * 2 - 7;
        int hxc[5];
#pragma unroll
        for (int t = 0; t < 5; ++t) hxc[t] = iclamp(hx0 + t, 0, 31);

        const float* kr = kh + hyc * 32;
        float acc[8];
#pragma unroll
        for (int i = 0; i < 8; ++i) acc[i] = 0.f;

        for (int c = 0; c < 128; ++c) {
            const float4 q4 = *(const float4*)&qs[c * 8 + pxg * 4];
            float qa[4] = {q4.x, q4.y, q4.z, q4.w};
            float kv[5];
#pragma unroll
            for (int t = 0; t < 5; ++t) kv[t] = kr[hxc[t]];
            kr += 1024;
#pragma unroll
            for (int i = 0; i < 4; ++i)
#pragma unroll
                for (int j = 0; j < 2; ++j) acc[i * 2 + j] += qa[i] * kv[i + j];
        }
#pragma unroll
        for (int i = 0; i < 4; ++i) {
            int px = pxg * 4 + i;
#pragma unroll
            for (int j = 0; j < 2; ++j) {
                int dx = dxg * 2 + j;
                int hx = hx0 + i + j;
                float val = -1e8f;
                if (vy && dx < 15 && hx >= 0 && hx < 32)
                    val = acc[i * 2 + j] + relh[(dy * 15 + dx) * 1024 + mm + px];
                qk[px * 242 + dy * 16 + dx] = val;
            }
        }
    }
    __syncthreads();

    // softmax: 32 threads per px, shuffle-reduce within 32-lane half-waves
    {
        int px = tid >> 5, s = tid & 31;
        float mx = -3.0e38f;
        for (int w = s; w < 240; w += 32) mx = fmaxf(mx, qk[px * 242 + w]);
#pragma unroll
        for (int msk = 16; msk; msk >>= 1) mx = fmaxf(mx, __shfl_xor(mx, msk));
        float sum = 0.f;
        for (int w = s; w < 240; w += 32) {
            float p = __expf(qk[px * 242 + w] - mx);
            qk[px * 242 + w] = p;
            sum += p;
        }
#pragma unroll
        for (int msk = 16; msk; msk >>= 1) sum += __shfl_xor(sum, msk);
        if (s == 0) invl[px] = 1.0f / sum;
    }
    __syncthreads();

    // write normalized attention back (coalesced-ish: px contiguous per w)
    for (int e = tid; e < 1800; e += 256) {
        int px = e & 7, w = e >> 3;        // w in 0..224
        int dy = w / 15, dx = w - dy * 15;
        relh[w * 1024 + mm + px] = qk[px * 242 + dy * 16 + dx] * invl[px];
    }
}

// ---------------------------------------------------------------------------
// PV gather: block = (4x8 px tile, 16-channel group, ng). 2048 blocks, no LDS.
// thread = (px 32, cs 8) owning 2 channels. V working set/block ~25KB -> L1.
// ---------------------------------------------------------------------------
__global__ __launch_bounds__(256)
void pv_kernel(const float* __restrict__ vp, const float* __restrict__ attn,
               float* __restrict__ agg)
{
    const int tid = threadIdx.x;
    const int px = tid & 31, cs = tid >> 5;
    const int py = px >> 3, pxx = px & 7;
    const int y0 = (blockIdx.x >> 2) * 4, x0 = (blockIdx.x & 3) * 8;
    const int cg = blockIdx.y;
    const int bz = blockIdx.z;
    const int n = bz >> 1, g = bz & 1;
    const int c0 = cg * 16 + cs * 2;
    const float* vb = vp + ((long)(n * 256 + g * 128) << 10) + ((long)c0 << 10);
    const float* ah = attn + (long)bz * 230400;
    const int m = (y0 + py) * 32 + x0 + pxx;

    float a0 = 0.f, a1 = 0.f;
    for (int dy = 0; dy < 15; ++dy) {
        int hyc = iclamp(y0 + py + dy - 7, 0, 31);
        const float* vrow = vb + hyc * 32;
        const float* arow = ah + (dy * 15) * 1024 + m;
#pragma unroll
        for (int dx = 0; dx < 15; ++dx) {
            float p = arow[dx * 1024];
            if (p != 0.f) {
                int col = iclamp(x0 + pxx + dx - 7, 0, 31);
                a0 += p * vrow[col];
                a1 += p * vrow[col + 1024];
            }
        }
    }
    float* ag = agg + ((long)n << 18) + ((long)(g * 128 + c0) << 10) + m;
    ag[0] = a0;
    ag[1024] = a1;
}

// ---------------------------------------------------------------------------
// ws floats: qp[1048576] kp[1048576] vp[1048576] rel/attn[1843200] agg[1048576]
// ---------------------------------------------------------------------------
extern "C" void kernel_launch(void* const* d_in, const int* in_sizes, int n_in,
                              void* d_out, int out_size, void* d_ws, size_t ws_size,
                              hipStream_t stream)
{
    const float* q    = (const float*)d_in[0];
    const float* k    = (const float*)d_in[1];
    const float* v    = (const float*)d_in[2];
    const float* Wq   = (const float*)d_in[3];
    const float* bq   = (const float*)d_in[4];
    const float* Wk   = (const float*)d_in[5];
    const float* bk   = (const float*)d_in[6];
    const float* Wv   = (const float*)d_in[7];
    const float* bv   = (const float*)d_in[8];
    const float* Wrel = (const float*)d_in[9];
    const float* brel = (const float*)d_in[10];
    const float* Vb   = (const float*)d_in[11];
    const float* Wfc  = (const float*)d_in[12];
    const float* bfc  = (const float*)d_in[13];
    float* out = (float*)d_out;

    float* ws  = (float*)d_ws;
    float* qp  = ws;
    float* kp  = ws + 1048576;
    float* vp  = ws + 2097152;
    float* rel = ws + 3145728;      // 8*225*1024, becomes attn in place
    float* agg = ws + 4988928;      // [n][256][1024]

    dim3 blk(256);

    // zero-init atomic accumulation targets (capture-safe memset nodes)
    hipMemsetAsync(qp, 0, (size_t)3 * 1048576 * 4, stream);          // qp,kp,vp
    hipMemsetAsync(rel, 0, (size_t)1843200 * 4, stream);
    hipMemsetAsync(out, 0, (size_t)out_size * 4, stream);

    // fused QKV projections, split-K=2: 16*4*24 = 1536 blocks
    qkv_kernel<<<dim3(16, 4, 24), blk, 0, stream>>>(q, k, v, Wq, Wk, Wv,
                                                    bq, bk, bv, qp, kp, vp, 2);

    // rel logits, split-K=2: 16*4*16 = 1024 blocks
    gemm_kernel<<<dim3(16, 4, 16), blk, 0, stream>>>(Wrel, qp, brel, rel,
        225, 128, 28800, 2, 131072, 230400, 225, 2, 4, 2, 0);

    // scores + softmax -> attn (in place over rel): 1024 blocks
    scores_kernel<<<dim3(128, 8), blk, 0, stream>>>(qp, kp, rel);

    // PV gather -> agg: 2048 blocks
    pv_kernel<<<dim3(32, 8, 8), blk, 0, stream>>>(vp, rel, agg);

    // V_bias aggregation (atomic add onto agg), split-K=3: 16*2*24 = 768 blocks
    gemm_kernel<<<dim3(16, 2, 24), blk, 0, stream>>>(Vb, rel, nullptr, agg,
        128, 225, 28800, 2, 230400, 131072, 0, 1, 4, 3, 0);

    // FC with interleaved [m][n][c] store, split-K=4: 16*4*16 = 1024 blocks
    gemm_kernel<<<dim3(16, 4, 16), blk, 0, stream>>>(Wfc, agg, bfc, out,
        256, 256, 0, 1, 262144, 0, 0, 1, 6, 4, 1024);
}

// Round 3
// 318.602 us; speedup vs baseline: 1.8067x; 1.8067x over previous
//
#include <hip/hip_runtime.h>
#include <math.h>

// N=4, C=256, H=W=32, NH=2, HD=128, MAX_DIS=7, WS=15, WW=225, T=sqrt(128)
// out: [hw=1024][n=4][c=256] fp32

__device__ __forceinline__ int iclamp(int v, int lo, int hi) {
    return v < lo ? lo : (v > hi ? hi : v);
}

// ---------------------------------------------------------------------------
// Shared GEMM body: Y(64x64 tile) = W[M,K] x X[K,1024] over k-tiles [kt0,kt1)
// flags: 2 = interleaved store (out[(col)*ldI + storeOff + row]),
//        4 = atomicAdd output. bias added only when addBias.
// All X/Y tensors have 1024 columns (hardcoded <<10).
// ---------------------------------------------------------------------------
__device__ __forceinline__
void gemm_body(const float* __restrict__ Wb, const float* __restrict__ Xb,
               const float* __restrict__ biasb, float* __restrict__ Yb,
               int M, int K, int kt0, int kt1, bool addBias, int flags,
               long storeOff, int ldI)
{
    __shared__ __align__(16) float sm[64 * 68];
    float* Ws = sm;              // [16][68] k-major, d contiguous
    float* Xs = sm + 16 * 68;    // [16][64] k-major, m contiguous

    const int row0 = blockIdx.y * 64;
    const int col0 = blockIdx.x * 64;
    const int tid = threadIdx.x;
    const int tx = tid & 15, ty = tid >> 4;

    float acc[4][4];
#pragma unroll
    for (int i = 0; i < 4; ++i)
#pragma unroll
        for (int j = 0; j < 4; ++j) acc[i][j] = 0.f;

    for (int kt = kt0; kt < kt1; ++kt) {
        const int c0 = kt * 16;
#pragma unroll
        for (int i = 0; i < 4; ++i) {
            int e = tid + i * 256;
            int cc = e & 15, dd = e >> 4;
            int gd = row0 + dd, gc = c0 + cc;
            float v = 0.f;
            if (gd < M && gc < K) v = Wb[(long)gd * K + gc];
            Ws[cc * 68 + dd] = v;
        }
#pragma unroll
        for (int i = 0; i < 4; ++i) {
            int e = tid + i * 256;
            int mm = e & 63, cc = e >> 6;
            int gc = c0 + cc;
            float v = 0.f;
            if (gc < K) v = Xb[((long)gc << 10) + col0 + mm];
            Xs[cc * 64 + mm] = v;
        }
        __syncthreads();
#pragma unroll
        for (int k = 0; k < 16; ++k) {
            const float4 a4 = *(const float4*)&Ws[k * 68 + ty * 4];
            const float4 b4 = *(const float4*)&Xs[k * 64 + tx * 4];
            float av[4] = {a4.x, a4.y, a4.z, a4.w};
            float bv[4] = {b4.x, b4.y, b4.z, b4.w};
#pragma unroll
            for (int i = 0; i < 4; ++i)
#pragma unroll
                for (int j = 0; j < 4; ++j) acc[i][j] += av[i] * bv[j];
        }
        __syncthreads();
    }

    if (!(flags & 2)) {
#pragma unroll
        for (int i = 0; i < 4; ++i) {
            int gd = row0 + ty * 4 + i;
            if (gd >= M) continue;
            float bvv = (addBias && biasb) ? biasb[gd] : 0.f;
            long yoff = ((long)gd << 10) + col0 + tx * 4;
            if (flags & 4) {
#pragma unroll
                for (int j = 0; j < 4; ++j)
                    atomicAdd(&Yb[yoff + j], acc[i][j] + bvv);
            } else {
                float4 r;
                r.x = acc[i][0] + bvv; r.y = acc[i][1] + bvv;
                r.z = acc[i][2] + bvv; r.w = acc[i][3] + bvv;
                *(float4*)&Yb[yoff] = r;
            }
        }
    } else {
        // interleaved store via LDS transpose (k-loop ended with barrier)
        float* tile = sm;  // [64 m][68 d]
#pragma unroll
        for (int i = 0; i < 4; ++i) {
            float bvv = (addBias && biasb) ? biasb[row0 + ty * 4 + i] : 0.f;
#pragma unroll
            for (int j = 0; j < 4; ++j)
                tile[(tx * 4 + j) * 68 + ty * 4 + i] = acc[i][j] + bvv;
        }
        __syncthreads();
#pragma unroll
        for (int it = 0; it < 16; ++it) {
            int e = tid + it * 256;
            int dd = e & 63, mm = e >> 6;
            long off = (long)(col0 + mm) * ldI + storeOff + row0 + dd;
            if (flags & 4) atomicAdd(&Yb[off], tile[mm * 68 + dd]);
            else Yb[off] = tile[mm * 68 + dd];
        }
    }
}

__global__ __launch_bounds__(256)
void gemm_kernel(const float* __restrict__ W, const float* __restrict__ X,
                 const float* __restrict__ bias, float* __restrict__ Y,
                 int M, int K, long wStride, int wMod,
                 long xStride, long yStride, int biasStride, int biasMod,
                 int flags, int kSplit, int ldI)
{
    int b = blockIdx.z / kSplit;
    int ks = blockIdx.z - b * kSplit;
    int ktiles = (K + 15) >> 4;
    int kt0 = ks * ktiles / kSplit, kt1 = (ks + 1) * ktiles / kSplit;
    const float* Wb = W + (long)(b % wMod) * wStride;
    const float* Xb = X + (long)b * xStride;
    const float* biasb = bias ? (bias + (long)(b % biasMod) * biasStride) : nullptr;
    float* Yb; long storeOff = 0;
    if (flags & 2) { Yb = Y; storeOff = (long)b * M; }
    else           { Yb = Y + (long)b * yStride; }
    gemm_body(Wb, Xb, biasb, Yb, M, K, kt0, kt1, ks == 0, flags, storeOff, ldI);
}

// Q,K,V projections fused into one dispatch: blockIdx.z = sel*4 + batch
__global__ __launch_bounds__(256)
void qkv_kernel(const float* __restrict__ q, const float* __restrict__ k,
                const float* __restrict__ v,
                const float* __restrict__ Wq, const float* __restrict__ Wk,
                const float* __restrict__ Wv,
                const float* __restrict__ bq, const float* __restrict__ bk,
                const float* __restrict__ bv,
                float* __restrict__ qp, float* __restrict__ kp,
                float* __restrict__ vp)
{
    int b = blockIdx.z;
    int sel = b >> 2, batch = b & 3;
    const float *W, *X, *bias; float* Y;
    if (sel == 0)      { W = Wq; X = q; bias = bq; Y = qp; }
    else if (sel == 1) { W = Wk; X = k; bias = bk; Y = kp; }
    else               { W = Wv; X = v; bias = bv; Y = vp; }
    gemm_body(W, X + ((long)batch << 18), bias, Y + ((long)batch << 18),
              256, 256, 0, 16, true, 0, 0, 0);
}

// ---------------------------------------------------------------------------
// scores + softmax: block = (ng, 1x8 pixel-row tile). 1024 blocks, ~12KB LDS.
// Reads rel logits from relattn, writes normalized attention back in place.
// ---------------------------------------------------------------------------
__global__ __launch_bounds__(256)
void scores_kernel(const float* __restrict__ qp, const float* __restrict__ kp,
                   float* __restrict__ relattn)
{
    __shared__ __align__(16) float qs[128 * 8];   // [c][8 px], scaled by 1/T
    __shared__ float qk[8 * 242];                 // [px][15*16 + 2]
    __shared__ float invl[8];

    const int tid = threadIdx.x;
    const int row = blockIdx.x >> 2;          // 0..31
    const int x0 = (blockIdx.x & 3) * 8;
    const int bz = blockIdx.y;                // n*2+g
    const long hoff = (long)((bz >> 1) * 256 + (bz & 1) * 128) << 10;
    const float* qh = qp + hoff;
    const float* kh = kp + hoff;
    float* relh = relattn + (long)bz * 230400;
    const int mm = row * 32 + x0;
    const float invT = 0.08838834764831845f;  // 1/sqrt(128)

    for (int e = tid; e < 1024; e += 256) {
        int c = e >> 3, px = e & 7;
        qs[c * 8 + px] = qh[((long)c << 10) + mm + px] * invT;
    }
    __syncthreads();

    // 240 tasks: (dy 15) x (pxg 2: 4px) x (dxg 8: 2dx)
    if (tid < 240) {
        int dy = tid >> 4;
        int r = tid & 15;
        int pxg = r & 1, dxg = r >> 1;
        int hy = row + dy - 7;
        int hyc = iclamp(hy, 0, 31);
        bool vy = (hy >= 0) && (hy < 32);
        int hx0 = x0 + pxg * 4 + dxg * 2 - 7;
        int hxc[5];
#pragma unroll
        for (int t = 0; t < 5; ++t) hxc[t] = iclamp(hx0 + t, 0, 31);

        const float* kr = kh + hyc * 32;
        float acc[8];
#pragma unroll
        for (int i = 0; i < 8; ++i) acc[i] = 0.f;

        for (int c = 0; c < 128; ++c) {
            const float4 q4 = *(const float4*)&qs[c * 8 + pxg * 4];
            float qa[4] = {q4.x, q4.y, q4.z, q4.w};
            float kv[5];
#pragma unroll
            for (int t = 0; t < 5; ++t) kv[t] = kr[hxc[t]];
            kr += 1024;
#pragma unroll
            for (int i = 0; i < 4; ++i)
#pragma unroll
                for (int j = 0; j < 2; ++j) acc[i * 2 + j] += qa[i] * kv[i + j];
        }
#pragma unroll
        for (int i = 0; i < 4; ++i) {
            int px = pxg * 4 + i;
#pragma unroll
            for (int j = 0; j < 2; ++j) {
                int dx = dxg * 2 + j;
                int hx = hx0 + i + j;
                float val = -1e8f;
                if (vy && dx < 15 && hx >= 0 && hx < 32)
                    val = acc[i * 2 + j] + relh[(dy * 15 + dx) * 1024 + mm + px];
                qk[px * 242 + dy * 16 + dx] = val;
            }
        }
    }
    __syncthreads();

    // softmax: 32 threads per px, shuffle-reduce within 32-lane half-waves
    {
        int px = tid >> 5, s = tid & 31;
        float mx = -3.0e38f;
        for (int w = s; w < 240; w += 32) mx = fmaxf(mx, qk[px * 242 + w]);
#pragma unroll
        for (int msk = 16; msk; msk >>= 1) mx = fmaxf(mx, __shfl_xor(mx, msk));
        float sum = 0.f;
        for (int w = s; w < 240; w += 32) {
            float p = __expf(qk[px * 242 + w] - mx);
            qk[px * 242 + w] = p;
            sum += p;
        }
#pragma unroll
        for (int msk = 16; msk; msk >>= 1) sum += __shfl_xor(sum, msk);
        if (s == 0) invl[px] = 1.0f / sum;
    }
    __syncthreads();

    // write normalized attention back (px contiguous per w)
    for (int e = tid; e < 1800; e += 256) {
        int px = e & 7, w = e >> 3;        // w in 0..224
        int dy = w / 15, dx = w - dy * 15;
        relh[w * 1024 + mm + px] = qk[px * 242 + dy * 16 + dx] * invl[px];
    }
}

// ---------------------------------------------------------------------------
// PV gather + V_bias fold: agg[c][m] = sum_w p[w][m] * (Vgather[c][w][m] + Vb[c][w])
// block = (cgrp of 4 channels, ng). 256 blocks x 256 threads.
// thread = one x-quad (4 px) x 4 channels, sliding V window in registers.
// ---------------------------------------------------------------------------
__global__ __launch_bounds__(256)
void pv_kernel(const float* __restrict__ vp, const float* __restrict__ attn,
               const float* __restrict__ Vbias, float* __restrict__ agg)
{
    __shared__ float vbs[4 * 225 + 4];
    const int tid = threadIdx.x;
    const int cgrp = blockIdx.x;        // 0..31
    const int bz = blockIdx.y;          // n*2+g
    const int n = bz >> 1, g = bz & 1;
    const int c0 = cgrp * 4;            // channel within head

    for (int e = tid; e < 900; e += 256) {
        int j = e / 225, w = e - j * 225;
        vbs[j * 225 + w] = Vbias[(g * 128 + c0 + j) * 225 + w];
    }
    __syncthreads();

    const int y = tid >> 3, x0 = (tid & 7) * 4;
    const float* ah = attn + (long)bz * 230400 + y * 32 + x0;
    const float* vb = vp + ((long)(n * 256 + g * 128 + c0) << 10);
    const int hx0 = x0 - 7;

    float acc[4][4];
#pragma unroll
    for (int j = 0; j < 4; ++j)
#pragma unroll
        for (int i = 0; i < 4; ++i) acc[j][i] = 0.f;

    for (int dy = 0; dy < 15; ++dy) {
        int hy = y + dy - 7;
        if (hy < 0 || hy > 31) continue;          // all p == 0 for this dy
        const float* vrow = vb + hy * 32;
        float win[4][4];
#pragma unroll
        for (int j = 0; j < 4; ++j)
#pragma unroll
            for (int t = 0; t < 4; ++t)
                win[j][t] = vrow[j * 1024 + iclamp(hx0 + t, 0, 31)];
        const float* arow = ah + (long)(dy * 15) * 1024;
        const float* vbrow = &vbs[dy * 15];
#pragma unroll
        for (int dx = 0; dx < 15; ++dx) {
            float4 p4 = *(const float4*)&arow[(long)dx * 1024];
            float pp[4] = {p4.x, p4.y, p4.z, p4.w};
#pragma unroll
            for (int j = 0; j < 4; ++j) {
                float vbj = vbrow[j * 225 + dx];
#pragma unroll
                for (int i = 0; i < 4; ++i)
                    acc[j][i] += pp[i] * (win[j][i] + vbj);
            }
            if (dx < 14) {
                int nc = iclamp(hx0 + dx + 4, 0, 31);
#pragma unroll
                for (int j = 0; j < 4; ++j) {
                    win[j][0] = win[j][1]; win[j][1] = win[j][2];
                    win[j][2] = win[j][3];
                    win[j][3] = vrow[j * 1024 + nc];
                }
            }
        }
    }

    float* ag = agg + ((long)n << 18) + ((long)(g * 128 + c0) << 10) + y * 32 + x0;
#pragma unroll
    for (int j = 0; j < 4; ++j) {
        float4 r;
        r.x = acc[j][0]; r.y = acc[j][1]; r.z = acc[j][2]; r.w = acc[j][3];
        *(float4*)&ag[(long)j * 1024] = r;
    }
}

// ---------------------------------------------------------------------------
// ws floats: qp[1048576] kp[1048576] vp[1048576] rel/attn[1843200] agg[1048576]
// ---------------------------------------------------------------------------
extern "C" void kernel_launch(void* const* d_in, const int* in_sizes, int n_in,
                              void* d_out, int out_size, void* d_ws, size_t ws_size,
                              hipStream_t stream)
{
    const float* q    = (const float*)d_in[0];
    const float* k    = (const float*)d_in[1];
    const float* v    = (const float*)d_in[2];
    const float* Wq   = (const float*)d_in[3];
    const float* bq   = (const float*)d_in[4];
    const float* Wk   = (const float*)d_in[5];
    const float* bk   = (const float*)d_in[6];
    const float* Wv   = (const float*)d_in[7];
    const float* bv   = (const float*)d_in[8];
    const float* Wrel = (const float*)d_in[9];
    const float* brel = (const float*)d_in[10];
    const float* Vb   = (const float*)d_in[11];
    const float* Wfc  = (const float*)d_in[12];
    const float* bfc  = (const float*)d_in[13];
    float* out = (float*)d_out;

    float* ws  = (float*)d_ws;
    float* qp  = ws;
    float* kp  = ws + 1048576;
    float* vp  = ws + 2097152;
    float* rel = ws + 3145728;      // 8*225*1024, becomes attn in place
    float* agg = ws + 4988928;      // [n][256][1024]

    dim3 blk(256);

    // FC uses split-K atomics -> zero out (capture-safe memset node)
    hipMemsetAsync(out, 0, (size_t)out_size * 4, stream);

    // fused QKV projections: 16*4*12 = 768 blocks, direct store
    qkv_kernel<<<dim3(16, 4, 12), blk, 0, stream>>>(q, k, v, Wq, Wk, Wv,
                                                    bq, bk, bv, qp, kp, vp);

    // rel logits: 16*4*8 = 512 blocks, direct store
    gemm_kernel<<<dim3(16, 4, 8), blk, 0, stream>>>(Wrel, qp, brel, rel,
        225, 128, 28800, 2, 131072, 230400, 225, 2, 0, 1, 0);

    // scores + softmax -> attn (in place over rel): 1024 blocks
    scores_kernel<<<dim3(128, 8), blk, 0, stream>>>(qp, kp, rel);

    // PV gather + V_bias fold -> agg: 256 blocks
    pv_kernel<<<dim3(32, 8), blk, 0, stream>>>(vp, rel, Vb, agg);

    // FC with interleaved [m][n][c] store, split-K=2: 16*4*8 = 512 blocks
    gemm_kernel<<<dim3(16, 4, 8), blk, 0, stream>>>(Wfc, agg, bfc, out,
        256, 256, 0, 1, 262144, 0, 0, 1, 6, 2, 1024);
}

// Round 4
// 228.716 us; speedup vs baseline: 2.5168x; 1.3930x over previous
//
#include <hip/hip_runtime.h>
#include <math.h>

// N=4, C=256, H=W=32, NH=2, HD=128, MAX_DIS=7, WS=15, WW=225, T=sqrt(128)
// out: [hw=1024][n=4][c=256] fp32

__device__ __forceinline__ int iclamp(int v, int lo, int hi) {
    return v < lo ? lo : (v > hi ? hi : v);
}

// ---------------------------------------------------------------------------
// Tiled fp32 GEMM body: Y(64x64 tile) = W[M,K] x X[K,1024], BK=32.
// flags: 2 = interleaved store (Y[(col)*ldI + storeOff + row]), 4 = atomicAdd.
// K must be a multiple of 32 (K in {128, 256}). X/Y have 1024 columns.
// ---------------------------------------------------------------------------
__device__ __forceinline__
void gemm_body(const float* __restrict__ Wb, const float* __restrict__ Xb,
               const float* __restrict__ biasb, float* __restrict__ Yb,
               int M, int K, int kt0, int kt1, bool addBias, int flags,
               long storeOff, int ldI)
{
    __shared__ __align__(16) float sm[64 * 68];   // 17.4 KB
    float* Ws = sm;               // [32][68] k-major, d contiguous
    float* Xs = sm + 32 * 68;     // [32][64] k-major, m contiguous

    const int row0 = blockIdx.y * 64;
    const int col0 = blockIdx.x * 64;
    const int tid = threadIdx.x;
    const int tx = tid & 15, ty = tid >> 4;

    float acc[4][4];
#pragma unroll
    for (int i = 0; i < 4; ++i)
#pragma unroll
        for (int j = 0; j < 4; ++j) acc[i][j] = 0.f;

    for (int kt = kt0; kt < kt1; ++kt) {
        const int c0 = kt * 32;
        // W tile: 64 d x 32 c, float4 loads, transposed scalar stores
#pragma unroll
        for (int i = 0; i < 2; ++i) {
            int e = tid + i * 256;
            int dd = e >> 3, c4 = (e & 7) * 4;
            int gd = row0 + dd;
            float4 w4 = make_float4(0.f, 0.f, 0.f, 0.f);
            if (gd < M) w4 = *(const float4*)&Wb[(long)gd * K + c0 + c4];
            Ws[(c4 + 0) * 68 + dd] = w4.x;
            Ws[(c4 + 1) * 68 + dd] = w4.y;
            Ws[(c4 + 2) * 68 + dd] = w4.z;
            Ws[(c4 + 3) * 68 + dd] = w4.w;
        }
        // X tile: 32 c x 64 m, float4 in, float4 out
#pragma unroll
        for (int i = 0; i < 2; ++i) {
            int e = tid + i * 256;
            int cc = e >> 4, m4 = (e & 15) * 4;
            float4 x4 = *(const float4*)&Xb[((long)(c0 + cc) << 10) + col0 + m4];
            *(float4*)&Xs[cc * 64 + m4] = x4;
        }
        __syncthreads();
#pragma unroll
        for (int k = 0; k < 32; ++k) {
            const float4 a4 = *(const float4*)&Ws[k * 68 + ty * 4];
            const float4 b4 = *(const float4*)&Xs[k * 64 + tx * 4];
            float av[4] = {a4.x, a4.y, a4.z, a4.w};
            float bv[4] = {b4.x, b4.y, b4.z, b4.w};
#pragma unroll
            for (int i = 0; i < 4; ++i)
#pragma unroll
                for (int j = 0; j < 4; ++j) acc[i][j] += av[i] * bv[j];
        }
        __syncthreads();
    }

    if (!(flags & 2)) {
#pragma unroll
        for (int i = 0; i < 4; ++i) {
            int gd = row0 + ty * 4 + i;
            if (gd >= M) continue;
            float bvv = (addBias && biasb) ? biasb[gd] : 0.f;
            long yoff = ((long)gd << 10) + col0 + tx * 4;
            if (flags & 4) {
#pragma unroll
                for (int j = 0; j < 4; ++j)
                    atomicAdd(&Yb[yoff + j], acc[i][j] + bvv);
            } else {
                float4 r;
                r.x = acc[i][0] + bvv; r.y = acc[i][1] + bvv;
                r.z = acc[i][2] + bvv; r.w = acc[i][3] + bvv;
                *(float4*)&Yb[yoff] = r;
            }
        }
    } else {
        // interleaved store via LDS transpose
        float* tile = sm;  // [64 m][68 d]
#pragma unroll
        for (int i = 0; i < 4; ++i) {
            float bvv = (addBias && biasb) ? biasb[row0 + ty * 4 + i] : 0.f;
#pragma unroll
            for (int j = 0; j < 4; ++j)
                tile[(tx * 4 + j) * 68 + ty * 4 + i] = acc[i][j] + bvv;
        }
        __syncthreads();
#pragma unroll
        for (int it = 0; it < 16; ++it) {
            int e = tid + it * 256;
            int dd = e & 63, mm = e >> 6;
            long off = (long)(col0 + mm) * ldI + storeOff + row0 + dd;
            if (flags & 4) atomicAdd(&Yb[off], tile[mm * 68 + dd]);
            else Yb[off] = tile[mm * 68 + dd];
        }
    }
}

__global__ __launch_bounds__(256)
void gemm_kernel(const float* __restrict__ W, const float* __restrict__ X,
                 const float* __restrict__ bias, float* __restrict__ Y,
                 int M, int K, long wStride, int wMod,
                 long xStride, long yStride, int biasStride, int biasMod,
                 int flags, int kSplit, int ldI)
{
    int b = blockIdx.z / kSplit;
    int ks = blockIdx.z - b * kSplit;
    int ktiles = (K + 31) >> 5;
    int kt0 = ks * ktiles / kSplit, kt1 = (ks + 1) * ktiles / kSplit;
    const float* Wb = W + (long)(b % wMod) * wStride;
    const float* Xb = X + (long)b * xStride;
    const float* biasb = bias ? (bias + (long)(b % biasMod) * biasStride) : nullptr;
    float* Yb; long storeOff = 0;
    if (flags & 2) { Yb = Y; storeOff = (long)b * M; }
    else           { Yb = Y + (long)b * yStride; }
    gemm_body(Wb, Xb, biasb, Yb, M, K, kt0, kt1, ks == 0, flags, storeOff, ldI);
}

// Q,K,V projections fused into one dispatch: blockIdx.z = sel*4 + batch
__global__ __launch_bounds__(256)
void qkv_kernel(const float* __restrict__ q, const float* __restrict__ k,
                const float* __restrict__ v,
                const float* __restrict__ Wq, const float* __restrict__ Wk,
                const float* __restrict__ Wv,
                const float* __restrict__ bq, const float* __restrict__ bk,
                const float* __restrict__ bv,
                float* __restrict__ qp, float* __restrict__ kp,
                float* __restrict__ vp)
{
    int b = blockIdx.z;
    int sel = b >> 2, batch = b & 3;
    const float *W, *X, *bias; float* Y;
    if (sel == 0)      { W = Wq; X = q; bias = bq; Y = qp; }
    else if (sel == 1) { W = Wk; X = k; bias = bk; Y = kp; }
    else               { W = Wv; X = v; bias = bv; Y = vp; }
    gemm_body(W, X + ((long)batch << 18), bias, Y + ((long)batch << 18),
              256, 256, 0, 8, true, 0, 0, 0);
}

// ---------------------------------------------------------------------------
// scores + softmax: block = (y row, ng). grid (32,8) = 256 blocks, 256 thr.
// thread = (c-half, dy, x-quad): acc[4 px][15 dx], sliding K window of 20
// floats (5 aligned float4 loads per channel) -> 60 FMA per channel.
// Partials from the two c-halves combine in LDS; softmax in-block; writes
// normalized attention back over the rel buffer.
// LDS: qs 16 KB + qk 30.8 KB = ~47.4 KB.
// ---------------------------------------------------------------------------
__global__ __launch_bounds__(256)
void scores_kernel(const float* __restrict__ qp, const float* __restrict__ kp,
                   float* __restrict__ relattn)
{
    __shared__ __align__(16) float qs[128 * 32];   // [c][x], scaled by 1/T
    __shared__ float qk[32 * 241];                 // [px][15*16 + pad]
    __shared__ float invl[32];

    const int tid = threadIdx.x;
    const int y = blockIdx.x;                 // 0..31
    const int bz = blockIdx.y;                // n*2+g
    const long hoff = (long)((bz >> 1) * 256 + (bz & 1) * 128) << 10;
    const float* qh = qp + hoff;
    const float* kh = kp + hoff;
    float* relh = relattn + (long)bz * 230400;
    const float invT = 0.08838834764831845f;  // 1/sqrt(128)

    // stage q row y: [128 c][32 x]
    for (int e = tid; e < 4096; e += 256) {
        int c = e >> 5, x = e & 31;
        qs[e] = qh[((long)c << 10) + y * 32 + x] * invT;
    }
    __syncthreads();

    const int ch = tid >> 7;          // c-half: 0/1
    const int r = tid & 127;
    const int dy = r >> 3;            // 0..15 (15 inactive)
    const int xq = r & 7;
    const int x0 = xq * 4;
    const bool active = (dy < 15);
    const int ky = y + dy - 7;        // may be out of [0,32): unclamped read,
                                      // memory-safe inside ws, masked below
    float acc[4][15];
#pragma unroll
    for (int i = 0; i < 4; ++i)
#pragma unroll
        for (int dx = 0; dx < 15; ++dx) acc[i][dx] = 0.f;

    if (active) {
        const float* kr = kh + (long)ky * 32 + (x0 - 8);   // 16B-aligned base
        const int cbase = ch * 64;
#pragma unroll 2
        for (int cc = 0; cc < 64; ++cc) {
            const int c = cbase + cc;
            const float4* p4 = (const float4*)(kr + ((long)c << 10));
            float4 w0 = p4[0], w1 = p4[1], w2 = p4[2], w3 = p4[3], w4 = p4[4];
            float w[20] = {w0.x, w0.y, w0.z, w0.w, w1.x, w1.y, w1.z, w1.w,
                           w2.x, w2.y, w2.z, w2.w, w3.x, w3.y, w3.z, w3.w,
                           w4.x, w4.y, w4.z, w4.w};
            const float4 q4 = *(const float4*)&qs[c * 32 + x0];
            float qa[4] = {q4.x, q4.y, q4.z, q4.w};
#pragma unroll
            for (int i = 0; i < 4; ++i)
#pragma unroll
                for (int dx = 0; dx < 15; ++dx)
                    acc[i][dx] += qa[i] * w[i + dx + 1];
        }
    }

    // combine: ch0 writes (with rel + mask), ch1 adds
    const bool vy = (ky >= 0) && (ky < 32);
    if (ch == 0 && active) {
#pragma unroll
        for (int i = 0; i < 4; ++i) {
            int px = x0 + i, m = y * 32 + px;
#pragma unroll
            for (int dx = 0; dx < 15; ++dx) {
                int hx = px + dx - 7;
                float val = -1e8f;
                if (vy && hx >= 0 && hx < 32)
                    val = acc[i][dx] + relh[((long)(dy * 15 + dx) << 10) + m];
                qk[px * 241 + dy * 16 + dx] = val;
            }
            qk[px * 241 + dy * 16 + 15] = -1e8f;   // pad slot
        }
    }
    __syncthreads();
    if (ch == 1 && active) {
#pragma unroll
        for (int i = 0; i < 4; ++i) {
            int px = x0 + i;
#pragma unroll
            for (int dx = 0; dx < 15; ++dx) {
                int hx = px + dx - 7;
                if (vy && hx >= 0 && hx < 32)
                    qk[px * 241 + dy * 16 + dx] += acc[i][dx];
            }
        }
    }
    __syncthreads();

    // softmax over 240 slots: 8 threads per px
    {
        int px = tid >> 3, s = tid & 7;
        float mx = -3.0e38f;
        for (int w = s; w < 240; w += 8) mx = fmaxf(mx, qk[px * 241 + w]);
#pragma unroll
        for (int msk = 4; msk; msk >>= 1) mx = fmaxf(mx, __shfl_xor(mx, msk));
        float sum = 0.f;
        for (int w = s; w < 240; w += 8) {
            float p = __expf(qk[px * 241 + w] - mx);
            qk[px * 241 + w] = p;
            sum += p;
        }
#pragma unroll
        for (int msk = 4; msk; msk >>= 1) sum += __shfl_xor(sum, msk);
        if (s == 0) invl[px] = 1.0f / sum;
    }
    __syncthreads();

    // write normalized attention back: coalesced 32-px rows per w
    for (int e = tid; e < 7200; e += 256) {
        int px = e & 31, w = e >> 5;      // w in 0..224
        int dy2 = w / 15, dx2 = w - dy2 * 15;
        relh[((long)w << 10) + y * 32 + px] = qk[px * 241 + dy2 * 16 + dx2] * invl[px];
    }
}

// ---------------------------------------------------------------------------
// PV gather + V_bias fold: agg[c][m] = sum_w p[w][m]*(Vgather[c][w][m]+Vb[c][w])
// block = (cgrp of 4 channels, ng). 256 blocks x 256 threads.
// ---------------------------------------------------------------------------
__global__ __launch_bounds__(256)
void pv_kernel(const float* __restrict__ vp, const float* __restrict__ attn,
               const float* __restrict__ Vbias, float* __restrict__ agg)
{
    __shared__ float vbs[4 * 225 + 4];
    const int tid = threadIdx.x;
    const int cgrp = blockIdx.x;        // 0..31
    const int bz = blockIdx.y;          // n*2+g
    const int n = bz >> 1, g = bz & 1;
    const int c0 = cgrp * 4;            // channel within head

    for (int e = tid; e < 900; e += 256) {
        int j = e / 225, w = e - j * 225;
        vbs[j * 225 + w] = Vbias[(g * 128 + c0 + j) * 225 + w];
    }
    __syncthreads();

    const int y = tid >> 3, x0 = (tid & 7) * 4;
    const float* ah = attn + (long)bz * 230400 + y * 32 + x0;
    const float* vb = vp + ((long)(n * 256 + g * 128 + c0) << 10);
    const int hx0 = x0 - 7;

    float acc[4][4];
#pragma unroll
    for (int j = 0; j < 4; ++j)
#pragma unroll
        for (int i = 0; i < 4; ++i) acc[j][i] = 0.f;

    for (int dy = 0; dy < 15; ++dy) {
        int hy = y + dy - 7;
        if (hy < 0 || hy > 31) continue;          // all p == 0 for this dy
        const float* vrow = vb + hy * 32;
        float win[4][4];
#pragma unroll
        for (int j = 0; j < 4; ++j)
#pragma unroll
            for (int t = 0; t < 4; ++t)
                win[j][t] = vrow[j * 1024 + iclamp(hx0 + t, 0, 31)];
        const float* arow = ah + (long)(dy * 15) * 1024;
        const float* vbrow = &vbs[dy * 15];
#pragma unroll
        for (int dx = 0; dx < 15; ++dx) {
            float4 p4 = *(const float4*)&arow[(long)dx * 1024];
            float pp[4] = {p4.x, p4.y, p4.z, p4.w};
#pragma unroll
            for (int j = 0; j < 4; ++j) {
                float vbj = vbrow[j * 225 + dx];
#pragma unroll
                for (int i = 0; i < 4; ++i)
                    acc[j][i] += pp[i] * (win[j][i] + vbj);
            }
            if (dx < 14) {
                int nc = iclamp(hx0 + dx + 4, 0, 31);
#pragma unroll
                for (int j = 0; j < 4; ++j) {
                    win[j][0] = win[j][1]; win[j][1] = win[j][2];
                    win[j][2] = win[j][3];
                    win[j][3] = vrow[j * 1024 + nc];
                }
            }
        }
    }

    float* ag = agg + ((long)n << 18) + ((long)(g * 128 + c0) << 10) + y * 32 + x0;
#pragma unroll
    for (int j = 0; j < 4; ++j) {
        float4 r;
        r.x = acc[j][0]; r.y = acc[j][1]; r.z = acc[j][2]; r.w = acc[j][3];
        *(float4*)&ag[(long)j * 1024] = r;
    }
}

// ---------------------------------------------------------------------------
// ws floats: qp[1048576] kp[1048576] vp[1048576] rel/attn[1843200] agg[1048576]
// ---------------------------------------------------------------------------
extern "C" void kernel_launch(void* const* d_in, const int* in_sizes, int n_in,
                              void* d_out, int out_size, void* d_ws, size_t ws_size,
                              hipStream_t stream)
{
    const float* q    = (const float*)d_in[0];
    const float* k    = (const float*)d_in[1];
    const float* v    = (const float*)d_in[2];
    const float* Wq   = (const float*)d_in[3];
    const float* bq   = (const float*)d_in[4];
    const float* Wk   = (const float*)d_in[5];
    const float* bk   = (const float*)d_in[6];
    const float* Wv   = (const float*)d_in[7];
    const float* bv   = (const float*)d_in[8];
    const float* Wrel = (const float*)d_in[9];
    const float* brel = (const float*)d_in[10];
    const float* Vb   = (const float*)d_in[11];
    const float* Wfc  = (const float*)d_in[12];
    const float* bfc  = (const float*)d_in[13];
    float* out = (float*)d_out;

    float* ws  = (float*)d_ws;
    float* qp  = ws;
    float* kp  = ws + 1048576;
    float* vp  = ws + 2097152;
    float* rel = ws + 3145728;      // 8*225*1024, becomes attn in place
    float* agg = ws + 4988928;      // [n][256][1024]

    dim3 blk(256);

    // FC uses split-K atomics -> zero out (capture-safe memset node)
    hipMemsetAsync(out, 0, (size_t)out_size * 4, stream);

    // fused QKV projections: 16*4*12 = 768 blocks, direct store
    qkv_kernel<<<dim3(16, 4, 12), blk, 0, stream>>>(q, k, v, Wq, Wk, Wv,
                                                    bq, bk, bv, qp, kp, vp);

    // rel logits: 16*4*8 = 512 blocks, direct store
    gemm_kernel<<<dim3(16, 4, 8), blk, 0, stream>>>(Wrel, qp, brel, rel,
        225, 128, 28800, 2, 131072, 230400, 225, 2, 0, 1, 0);

    // scores + softmax -> attn (in place over rel): 256 blocks
    scores_kernel<<<dim3(32, 8), blk, 0, stream>>>(qp, kp, rel);

    // PV gather + V_bias fold -> agg: 256 blocks
    pv_kernel<<<dim3(32, 8), blk, 0, stream>>>(vp, rel, Vb, agg);

    // FC with interleaved [m][n][c] store, split-K=2: 16*4*8 = 512 blocks
    gemm_kernel<<<dim3(16, 4, 8), blk, 0, stream>>>(Wfc, agg, bfc, out,
        256, 256, 0, 1, 262144, 0, 0, 1, 6, 2, 1024);
}